// Round 14
// baseline (68.734 us; speedup 1.0000x reference)
//
#include <hip/hip_runtime.h>
#include <utility>

#define NPB  2001      // outputs per task: 9+45+165+495+1287
#define ROWW 65        // row stride: 64 columns (one per lane) + 1 pad word
                       // (R13 bug: ROWW=57 < 64 cols -> row aliasing)

// Wave-internal LDS fence (each wave's LDS region is private).
#define WAVE_SYNC() asm volatile("s_waitcnt lgkmcnt(0)" ::: "memory")

typedef float vfloat4 __attribute__((ext_vector_type(4)));

// ---------- compile-time combinatorics (lex order == itertools CWR) ----------
struct Comp { int o; int ix[5]; };

constexpr long mscount(int n, int k) {   // multiset count M(n,k) = C(n+k-1,k)
  if (k <= 0) return 1;
  long num = 1, den = 1;
  for (int i = 0; i < k; ++i) { num *= (n + k - 1 - i); den *= (i + 1); }
  return num / den;
}
constexpr Comp comp(int s) {             // global output slot -> (order, indices)
  Comp c{1, {0, 0, 0, 0, 0}};
  int k, r;
  if (s < 9)        { k = 1; r = s; }
  else if (s < 54)  { k = 2; r = s - 9; }
  else if (s < 219) { k = 3; r = s - 54; }
  else if (s < 714) { k = 4; r = s - 219; }
  else              { k = 5; r = s - 714; }
  c.o = k;
  int cur = 0;
  for (int pos = 0; pos < k; ++pos) {
    for (int vv = cur; vv < 9; ++vv) {
      long cnt = mscount(9 - vv, k - pos - 1);
      if ((long)r < cnt) { c.ix[pos] = vv; cur = vv; break; }
      r -= (int)cnt;
    }
  }
  return c;
}

// ---------- compile-time unroll helper ----------
template<int S0, class F, int... Is>
__device__ __forceinline__ void unroll_impl(F&& f, std::integer_sequence<int, Is...>) {
  (f(std::integral_constant<int, S0 + Is>{}), ...);
}
template<int S0, int S1, class F>
__device__ __forceinline__ void unroll_range(F&& f) {
  unroll_impl<S0>(static_cast<F&&>(f), std::make_integer_sequence<int, S1 - S0>{});
}

// ---------- phase 1: lane=task, per-slot left-fold product -> transposed LDS --
// All factor indices compile-time -> v[] stays in registers, zero gathers.
template<int K>
__device__ __forceinline__ void chunk_write(const float (&v)[9], float* Lb, int lane) {
  constexpr int S0 = 32 * K;
  constexpr int NR = (S0 + 32 <= NPB) ? 32 : (NPB - S0);   // 32, last chunk 17
  unroll_range<0, NR>([&](auto rc) {
    constexpr int R = decltype(rc)::value;
    constexpr Comp C = comp(S0 + R);
    float p = v[C.ix[0]];                                  // left fold == jnp.prod
    if constexpr (C.o >= 2) p *= v[C.ix[1]];
    if constexpr (C.o >= 3) p *= v[C.ix[2]];
    if constexpr (C.o >= 4) p *= v[C.ix[3]];
    if constexpr (C.o >= 5) p *= v[C.ix[4]];
    Lb[R * ROWW + lane] = p;     // row = slot-in-chunk, col = lane (= task)
  });
}

// ---------- phase 2: transposed readback + 16B stores ----------
// 8 lanes per task: lane (u,q) handles tasks col=8i+u, elements rows 4q..4q+3.
template<bool LAST>
__device__ __forceinline__ void readback_store(
    const float* Lb, float* __restrict__ out, unsigned base,
    int G, int ntask, int u, int q) {
  #pragma unroll
  for (int i = 0; i < 8; ++i) {
    const int col = 8 * i + u;
    const int t = G + col;
    if (t >= ntask) continue;
    float* const po = out + (unsigned)t * (unsigned)NPB + base;
    if (!LAST || q < 4) {
      const float* p = Lb + 4 * q * ROWW + col;
      vfloat4 w = { p[0], p[ROWW], p[2 * ROWW], p[3 * ROWW] };
      __builtin_memcpy(po + 4 * q, &w, 16);   // 4B-alignment tolerant
    } else if (q == 4) {                      // last chunk has 17 slots
      po[16] = Lb[16 * ROWW + col];
    }
  }
}

template<int SL>
__device__ __forceinline__ void run_slice(
    const float (&v)[9], float* Lb, float* __restrict__ out,
    int G, int ntask, int u, int q, int lane) {
  unroll_range<SL * 7, SL * 7 + 7>([&](auto kc) {
    constexpr int K = decltype(kc)::value;
    chunk_write<K>(v, Lb, lane);
    WAVE_SYNC();                         // writes visible before cross-lane reads
    readback_store<(K == 62)>(Lb, out, 32u * (unsigned)K, G, ntask, u, q);
    WAVE_SYNC();                         // reads retired before next overwrite
  });
}

// One wave = 64 consecutive tasks x 7 chunks (slice). 9 slices per group.
__global__ __launch_bounds__(256) void poly_dfs_kernel(
    const float* __restrict__ x, float* __restrict__ out,
    int ntask, int ngroups) {
  __shared__ float L[4][32 * ROWW];      // 8320 B/wave, 33280 B/block
  const int wave = threadIdx.x >> 6;
  const int lane = threadIdx.x & 63;
  const int wid = blockIdx.x * 4 + wave;
  const int group = wid / 9;
  const int slice = wid - group * 9;
  if (group >= ngroups) return;          // waves independent: safe early exit
  const int G = group * 64;
  float* const Lb = L[wave];

  float v[9];                            // this lane's task singles (registers)
  {
    const int t = G + lane;
    const int tc = (t < ntask) ? t : (ntask - 1);   // clamp (stores are guarded)
    const float* xs = x + (size_t)tc * 9;
    #pragma unroll
    for (int i = 0; i < 9; ++i) v[i] = xs[i];
  }
  const int u = lane >> 3, q = lane & 7;

  switch (slice) {
    case 0: run_slice<0>(v, Lb, out, G, ntask, u, q, lane); break;
    case 1: run_slice<1>(v, Lb, out, G, ntask, u, q, lane); break;
    case 2: run_slice<2>(v, Lb, out, G, ntask, u, q, lane); break;
    case 3: run_slice<3>(v, Lb, out, G, ntask, u, q, lane); break;
    case 4: run_slice<4>(v, Lb, out, G, ntask, u, q, lane); break;
    case 5: run_slice<5>(v, Lb, out, G, ntask, u, q, lane); break;
    case 6: run_slice<6>(v, Lb, out, G, ntask, u, q, lane); break;
    case 7: run_slice<7>(v, Lb, out, G, ntask, u, q, lane); break;
    default: run_slice<8>(v, Lb, out, G, ntask, u, q, lane); break;
  }
}

extern "C" void kernel_launch(void* const* d_in, const int* in_sizes, int n_in,
                              void* d_out, int out_size, void* d_ws, size_t ws_size,
                              hipStream_t stream) {
  const float* x = (const float*)d_in[0];
  float* out = (float*)d_out;
  const int ntask = in_sizes[0] / 9;              // B * 35
  const int ngroups = (ntask + 63) / 64;
  const int nwaves = ngroups * 9;
  const int blocks = (nwaves + 3) / 4;
  poly_dfs_kernel<<<blocks, 256, 0, stream>>>(x, out, ntask, ngroups);
}

// Round 15
// 51.769 us; speedup vs baseline: 1.3277x; 1.3277x over previous
//
#include <hip/hip_runtime.h>

#define BSZ 9
#define NPB 2001   // 9 + 45 + 165 + 495 + 1287
#define N2 45
#define N3 165
#define N4 495
#define O2 9
#define O3 54
#define O4 219
#define ONE_SLOT 714
#define LSZ 720
#define NBLOCKS 1792              // 7168 waves; 35840/7168 = exactly 5 tasks/wave
#define STRIDE_T (NBLOCKS * 4)    // 7168; %4==0 keeps alignment class fixed

// Wave-internal LDS fence (each wave's LDS region is private).
#define WAVE_SYNC() asm volatile("s_waitcnt lgkmcnt(0)" ::: "memory")

// Native 16B vector type (HIP's float4 is a class; this one maps to v4f32).
typedef float vfloat4 __attribute__((ext_vector_type(4)));

constexpr unsigned pslot2(unsigned i, unsigned j) {   // slot of pair (i<=j)
    return O2 + i * 9u - i * (i - 1u) / 2u + (j - i);
}

// Staging tables: lo8 = source slot (<256), hi8 = single index.
struct Tabs { unsigned short p2[N2]; unsigned short p3[N3]; unsigned short p4[N4]; };
constexpr Tabs make_tabs() {
    Tabs t{};
    { int p = 0;
      for (unsigned i = 0; i < 9; ++i)
          for (unsigned j = i; j < 9; ++j)
              t.p2[p++] = (unsigned short)(i | (j << 8)); }
    { int p = 0;
      for (unsigned a = 0; a < 9; ++a)
          for (unsigned b = a; b < 9; ++b) {
              const unsigned ps = pslot2(a, b);
              for (unsigned c = b; c < 9; ++c)
                  t.p3[p++] = (unsigned short)(ps | (c << 8));
          } }
    { int p = 0; unsigned ts = O3;
      for (unsigned a = 0; a < 9; ++a)
          for (unsigned b = a; b < 9; ++b)
              for (unsigned c = b; c < 9; ++c) {
                  for (unsigned d = c; d < 9; ++d)
                      t.p4[p++] = (unsigned short)(ts | (d << 8));
                  ++ts;
              } }
    return t;
}
__constant__ Tabs g_tabs = make_tabs();

// Unified output table: out[j] = L[lo16 byte off] * L[hi16 byte off] (word o added
// via the shifted base pointer). Slot ONE_SLOT holds 1.0f.
struct Full { unsigned t[NPB]; };
constexpr Full make_full() {
    Full f{};
    for (unsigned j = 0; j < ONE_SLOT; ++j)
        f.t[j] = (4u * j) | ((4u * ONE_SLOT) << 16);
    { int p = ONE_SLOT; unsigned qs = O4;
      for (unsigned a = 0; a < 9; ++a)
          for (unsigned b = a; b < 9; ++b)
              for (unsigned c = b; c < 9; ++c)
                  for (unsigned d = c; d < 9; ++d) {
                      for (unsigned e = d; e < 9; ++e)
                          f.t[p++] = (4u * qs) | ((4u * e) << 16);
                      ++qs;
                  } }
    return f;
}
__constant__ Full g_full = make_full();

// Persistent: each wave owns tasks {w0, w0+7168, ...} (exactly 5 for B=1024).
__global__ __launch_bounds__(256) void poly_expand_kernel(
        const float* __restrict__ x, float* __restrict__ out, int ntask) {
    __shared__ float L[4][LSZ];
    const int wave = threadIdx.x >> 6;
    const int lane = threadIdx.x & 63;
    const int w0 = blockIdx.x * 4 + wave;
    if (w0 >= ntask) return;               // waves independent: safe
    float* const Lw = L[wave];

    // alignment geometry (loop-invariant: STRIDE_T % 4 == 0)
    const unsigned o     = (unsigned)w0 & 3u;           // rb & 3
    const unsigned a     = (4u - o) & 3u;               // head scalars
    const unsigned mA    = (ONE_SLOT - a) >> 2;         // full-A float4 groups
    const unsigned mB0   = (ONE_SLOT - a + 3u) >> 2;    // first full-B group
    const unsigned Mfull = (NPB - a) >> 2;              // == mB0 + 321
    float* const Ls = Lw + o;
    const char* const Lc = (const char*)Ls;
    const float* const Afp = Lw + o + a;                // (o+a)%4==0, 16B-aligned

    // ---- hoisted per-lane loop invariants (tables -> registers) ----
    const unsigned t2 = (lane < N2) ? (unsigned)g_tabs.p2[lane] : 0u;
    unsigned t3[3], t4[8];
    #pragma unroll
    for (int k = 0; k < 3; ++k) { const int s = lane + 64 * k;
        t3[k] = (s < N3) ? (unsigned)g_tabs.p3[s] : 0u; }
    #pragma unroll
    for (int k = 0; k < 8; ++k) { const int s = lane + 64 * k;
        t4[k] = (s < N4) ? (unsigned)g_tabs.p4[s] : 0u; }

    const unsigned jb0 = a + 4u * mB0;     // first B-group output index
    unsigned bpk[6][4];
    #pragma unroll
    for (int k = 0; k < 6; ++k) {
        const unsigned idx = (unsigned)lane + 64u * k;
        #pragma unroll
        for (int e = 0; e < 4; ++e)
            bpk[k][e] = (idx < 321u) ? g_full.t[jb0 + 4u * idx + (unsigned)e] : 0u;
    }

    // misc elements: head [0,a) + straddle [a+4mA, a+4mB0) + tail [a+4Mfull, NPB)
    const unsigned z1s = a + 4u * mA, z1n = 4u * (mB0 - mA);
    const unsigned z2s = a + 4u * Mfull, z2n = (unsigned)NPB - z2s;
    int jm = -1;
    if ((unsigned)lane < a)                 jm = lane;
    else if ((unsigned)lane < a + z1n)      jm = (int)(z1s + ((unsigned)lane - a));
    else if ((unsigned)lane < a + z1n + z2n) jm = (int)(z2s + ((unsigned)lane - a - z1n));
    const unsigned mpk = (jm >= 0) ? g_full.t[jm] : 0u;

    // constant 1.0 slot: written once (never overwritten by staging)
    if (lane == 9) Ls[ONE_SLOT] = 1.0f;

    // prefetch first x row
    float xreg = 0.0f;
    if (lane < 9) xreg = x[(size_t)w0 * BSZ + lane];

    // ---- persistent task loop ----
    for (int task = w0; task < ntask; task += STRIDE_T) {
        const unsigned rb = (unsigned)task * (unsigned)NPB;
        WAVE_SYNC();   // prior iteration's LDS reads retired before overwrite

        // stage singles from prefetched registers, then issue next prefetch
        if (lane < 9) Ls[lane] = xreg;          // waits vmcnt for xreg
        {
            const int nxt = task + STRIDE_T;
            if (lane < 9 && nxt < ntask) xreg = x[(size_t)nxt * BSZ + lane];
        }
        WAVE_SYNC();
        // pairs
        if (lane < N2) Ls[O2 + lane] = Ls[t2 & 255u] * Ls[t2 >> 8];
        WAVE_SYNC();
        // triples
        #pragma unroll
        for (int k = 0; k < 3; ++k) { const int s = lane + 64 * k;
            if (s < N3) Ls[O3 + s] = Ls[t3[k] & 255u] * Ls[t3[k] >> 8]; }
        WAVE_SYNC();
        // quads
        #pragma unroll
        for (int k = 0; k < 8; ++k) { const int s = lane + 64 * k;
            if (s < N4) Ls[O4 + s] = Ls[t4[k] & 255u] * Ls[t4[k] >> 8]; }
        WAVE_SYNC();

        float* const po = out + rb + a;        // 16B-aligned base

        // region A (orders<=4): straight LDS b128 -> global dwordx4
        #pragma unroll
        for (int k = 0; k < 3; ++k) {
            const unsigned m = (unsigned)lane + 64u * k;
            if (m < mA) {
                *(vfloat4*)(po + 4u * m) = *(const vfloat4*)(Afp + 4u * m);
            }
        }
        // region B (order 5): quad * single, hoisted byte-offset table
        #pragma unroll
        for (int k = 0; k < 6; ++k) {
            const unsigned idx = (unsigned)lane + 64u * k;
            if (idx < 321u) {
                vfloat4 r;
                #pragma unroll
                for (int e = 0; e < 4; ++e) {
                    const unsigned pk = bpk[k][e];
                    r[e] = *(const float*)(Lc + (pk & 0xFFFFu)) *
                           *(const float*)(Lc + (pk >> 16));
                }
                *(vfloat4*)(po + 4u * (mB0 + idx)) = r;
            }
        }
        // misc (<=9 lanes): head / straddle / tail scalars
        if (jm >= 0)
            out[rb + (unsigned)jm] = *(const float*)(Lc + (mpk & 0xFFFFu)) *
                                     *(const float*)(Lc + (mpk >> 16));
    }
}

extern "C" void kernel_launch(void* const* d_in, const int* in_sizes, int n_in,
                              void* d_out, int out_size, void* d_ws, size_t ws_size,
                              hipStream_t stream) {
    const float* x = (const float*)d_in[0];
    float* out = (float*)d_out;
    const int ntask = in_sizes[0] / BSZ;            // B * 35
    int blocks = (ntask + 3) / 4;
    if (blocks > NBLOCKS) blocks = NBLOCKS;
    poly_expand_kernel<<<blocks, 256, 0, stream>>>(x, out, ntask);
}